// Round 3
// baseline (4358.367 us; speedup 1.0000x reference)
//
#include <hip/hip_runtime.h>
#include <hip/hip_bf16.h>

// ClippedGRU: B=256, T=500, I=128, H=512, clip ±5. fp32 in/out, bf16 MFMA core.
//
// Persistent cooperative kernel. Grid = 256 blocks = 16 batch-groups (16 rows
// = MFMA M) x 16 unit-strips (32 h-units -> 96 rows of W_hh/W_ih). W strips
// live in registers as MFMA B-fragments (6 GEMM waves, 384 threads).
//
// Exchange (round-1 format, verified): bf16 h in a 2-slot global buffer,
// published as relaxed agent-scope 8B stores; per-(group,step) flag line of
// 16 bytes. This revision restructures the step critical path:
//  - hh GEMM A-fragments load DIRECTLY from hbuf into registers (2x8B atomic
//    loads per k-strip). No LDS staging, no barrier D. Producer j's 32-unit
//    strip == MFMA k-chunk j, so strips can be consumed per-flag as they
//    arrive (in-order slow path); steady state = all 16 flags already set ->
//    single flag-line read + 32 pipelined loads + 16 MFMAs.
//  - publish-first: gate waves store the 2 hbuf words, s_waitcnt vmcnt(0)
//    (ONLY publishes outstanding), then s_hold/out stores. Barrier H is raw;
//    the flag store never waits on out-store acks.
// Two barriers per step (F: s_g ordering; H: step rendezvous).
//
// Slot reuse safety (2 slots): publishing h_{t+1} is data-dependent on having
// consumed h_t (MFMA used the loads), which required peers' h_t publishes,
// which followed their consumption of h_{t-1} -> overwriting slot (t-1)&1 is
// safe.

#define T_STEPS 500
#define B_TOT   256
#define I_DIM   128
#define H_DIM   512
#define BB      16      // batch rows per group (= MFMA M)
#define UU      32      // h-units per block strip (= MFMA K per strip)
#define TPAD    512     // padded T for flag indexing
#define FLAGS_BYTES (16 * TPAD * 16)   // [group][t][block] bytes = 128 KB

typedef __bf16 bf16x8 __attribute__((ext_vector_type(8)));
typedef float  f32x4  __attribute__((ext_vector_type(4)));
typedef float  f32x8  __attribute__((ext_vector_type(8)));
typedef unsigned short u16;
typedef unsigned int   u32;
typedef unsigned long long u64;

__device__ __forceinline__ bf16x8 cvt8(const float* p) {
    f32x8 v = *(const f32x8*)p;   // 32B load (2x dwordx4)
    bf16x8 r;
#pragma unroll
    for (int i = 0; i < 8; ++i) r[i] = (__bf16)v[i];   // RNE cvt
    return r;
}

__device__ __forceinline__ float fast_sigmoid(float x) {
    float e = __builtin_amdgcn_exp2f(-1.4426950408889634f * x);
    return __builtin_amdgcn_rcpf(1.0f + e);
}
__device__ __forceinline__ float fast_tanh(float x) {
    float e = __builtin_amdgcn_exp2f(2.8853900817779268f * x);
    return 1.0f - 2.0f * __builtin_amdgcn_rcpf(1.0f + e);
}

// raw barrier, writer-side LDS drain only (no vmcnt drain)
#define BAR_LDS()                                              \
    do {                                                       \
        asm volatile("s_waitcnt lgkmcnt(0)" ::: "memory");     \
        __builtin_amdgcn_sched_barrier(0);                     \
        __builtin_amdgcn_s_barrier();                          \
        __builtin_amdgcn_sched_barrier(0);                     \
    } while (0)
#define BAR_RAW()                                              \
    do {                                                       \
        __builtin_amdgcn_sched_barrier(0);                     \
        __builtin_amdgcn_s_barrier();                          \
        __builtin_amdgcn_sched_barrier(0);                     \
    } while (0)

#define LD_AGENT(p) __hip_atomic_load((p), __ATOMIC_RELAXED, \
                                      __HIP_MEMORY_SCOPE_AGENT)

__global__ __launch_bounds__(384, 2)
void gru_persist(const float* __restrict__ x,
                 const float* __restrict__ h0,
                 const float* __restrict__ wih,
                 const float* __restrict__ whh,
                 const float* __restrict__ bih,
                 const float* __restrict__ bhh,
                 float* __restrict__ out,
                 unsigned char* __restrict__ flags,   // [16][TPAD][16], zeroed
                 __hip_bfloat16* __restrict__ hbuf)   // [2][256][512] bf16
{
    const int tid  = threadIdx.x;
    const int bx   = blockIdx.x;
    const int g    = bx >> 4;          // batch group 0..15
    const int j    = bx & 15;          // unit strip 0..15
    const int bg   = g * BB;           // batch base
    const int u0   = j * UU;           // unit base
    const int w    = tid >> 6;         // wave 0..5, all GEMM
    const int lane = tid & 63;
    const int lrow = lane & 15;        // MFMA m / n index within fragment
    const int lq   = lane >> 4;        // quad 0..3

    __shared__ float s_g[4][16 * 36];  // r, z, hh_n, xi_n (stride 36)
    __shared__ float s_hold[16 * 32];  // fp32 carried h strip (never rounded)
    __shared__ float s_bih[96];
    __shared__ float s_bhh[96];

    // ---- one-time init ----
    for (int i = tid; i < 512; i += 384) {
        int b = i >> 5, u = i & 31;
        s_hold[b * 32 + u] = h0[(size_t)(bg + b) * H_DIM + u0 + u];
    }
    if (tid < 96) {
        int gg = tid >> 5, uu = tid & 31;
        s_bih[tid] = bih[gg * H_DIM + u0 + uu];
        s_bhh[tid] = bhh[gg * H_DIM + u0 + uu];
    }

    // ---- one-time: W_hh / W_ih strips -> bf16 register B-fragments ----
    const int gate = w >> 1;
    const int hf   = w & 1;
    bf16x8 wf[16], wfi[4];
    {
        const long row0 = (long)gate * H_DIM + u0 + 16 * hf;  // row in [0,1536)
        const float* wr  = whh + (row0 + lrow) * H_DIM + lq * 8;
        const float* wr2 = wih + (row0 + lrow) * I_DIM + lq * 8;
#pragma unroll
        for (int kt = 0; kt < 16; ++kt) wf[kt] = cvt8(wr + kt * 32);
#pragma unroll
        for (int kt = 0; kt < 4; ++kt)  wfi[kt] = cvt8(wr2 + kt * 32);
    }
    __syncthreads();

    int sync_ok = 1;  // timeout latch (fail-fast, no hang)

#pragma unroll 1
    for (int t = 0; t < T_STEPS; ++t) {
        // ---- A: x fragment loads for step t (plain cached loads) ----
        const float* xr =
            x + ((size_t)(bg + lrow) * T_STEPS + t) * I_DIM + lq * 8;
        bf16x8 xf0 = cvt8(xr);
        bf16x8 xf1 = cvt8(xr + 32);
        bf16x8 xf2 = cvt8(xr + 64);
        bf16x8 xf3 = cvt8(xr + 96);

        // ---- B: early flag-line read (hides under ih GEMM) ----
        const u64* fl = (const u64*)(flags + ((size_t)g * TPAD + (t - 1)) * 16);
        u64 fa = 0, fb = 0;
        if (t > 0) { fa = LD_AGENT(fl); fb = LD_AGENT(fl + 1); }

        // ---- C: ih GEMM ----
        f32x4 acc[4] = {{0,0,0,0},{0,0,0,0},{0,0,0,0},{0,0,0,0}};
        f32x4 accX = {0, 0, 0, 0};
        {
            f32x4 ai = {0, 0, 0, 0};
            ai = __builtin_amdgcn_mfma_f32_16x16x32_bf16(xf0, wfi[0], ai, 0, 0, 0);
            ai = __builtin_amdgcn_mfma_f32_16x16x32_bf16(xf1, wfi[1], ai, 0, 0, 0);
            ai = __builtin_amdgcn_mfma_f32_16x16x32_bf16(xf2, wfi[2], ai, 0, 0, 0);
            ai = __builtin_amdgcn_mfma_f32_16x16x32_bf16(xf3, wfi[3], ai, 0, 0, 0);
            if (gate < 2) acc[0] = ai; else accX = ai;
        }

        // ---- D: hh GEMM, A-fragments straight from global ----
        if (t == 0) {
            const float* hr0 = h0 + (size_t)(bg + lrow) * H_DIM + lq * 8;
#pragma unroll
            for (int p = 0; p < 16; ++p) {
                bf16x8 hfr = cvt8(hr0 + p * 32);
                acc[p & 3] = __builtin_amdgcn_mfma_f32_16x16x32_bf16(
                    hfr, wf[p], acc[p & 3], 0, 0, 0);
            }
        } else {
            // row base for this lane's batch row; strip p = u64 [8p+2lq, +2)
            const u64* hrow = (const u64*)(hbuf +
                (size_t)(t & 1) * B_TOT * H_DIM +
                (size_t)(bg + lrow) * H_DIM) + 2 * lq;
            const u64 ALL = 0x0101010101010101ull;
            if (fa == ALL && fb == ALL) {
                asm volatile("" ::: "memory");   // loads stay below the check
                u64 qv[32];
#pragma unroll
                for (int p = 0; p < 16; ++p) {
                    qv[2 * p]     = LD_AGENT(hrow + 8 * p);
                    qv[2 * p + 1] = LD_AGENT(hrow + 8 * p + 1);
                }
#pragma unroll
                for (int p = 0; p < 16; ++p) {
                    union { u64 q[2]; bf16x8 v; } uf;
                    uf.q[0] = qv[2 * p];
                    uf.q[1] = qv[2 * p + 1];
                    acc[p & 3] = __builtin_amdgcn_mfma_f32_16x16x32_bf16(
                        uf.v, wf[p], acc[p & 3], 0, 0, 0);
                }
            } else {
                // slow path: consume strips in order as flags arrive
                long tries = 0;
#pragma unroll
                for (int p = 0; p < 16; ++p) {
                    const u64 need = 0xFFull << (8 * (p & 7));
                    for (;;) {
                        u64 word = (p < 8) ? fa : fb;
                        if ((word & need) != 0 || !sync_ok) break;
                        __builtin_amdgcn_s_sleep(1);
                        if (++tries > (1L << 20)) { sync_ok = 0; break; }
                        fa = LD_AGENT(fl);
                        fb = LD_AGENT(fl + 1);
                    }
                    asm volatile("" ::: "memory");
                    union { u64 q[2]; bf16x8 v; } uf;
                    uf.q[0] = LD_AGENT(hrow + 8 * p);
                    uf.q[1] = LD_AGENT(hrow + 8 * p + 1);
                    acc[p & 3] = __builtin_amdgcn_mfma_f32_16x16x32_bf16(
                        uf.v, wf[p], acc[p & 3], 0, 0, 0);
                }
            }
        }

        // ---- E: write gate partials to LDS ----
        {
            f32x4 sum = acc[0] + acc[1] + acc[2] + acc[3];
            const int col = hf * 16 + lrow;
#pragma unroll
            for (int i = 0; i < 4; ++i) {
                int b = lq * 4 + i;
                s_g[gate][b * 36 + col] = sum[i];
                if (gate == 2) s_g[3][b * 36 + col] = accX[i];
            }
        }
        BAR_LDS();                                     // F

        // ---- G: gate math, 128 threads x 4 units; publish FIRST ----
        if (tid < 128) {
            const int b  = tid >> 3;
            const int ub = (tid & 7) * 4;
            f32x4 vr  = *(const f32x4*)&s_g[0][b * 36 + ub];
            f32x4 vz  = *(const f32x4*)&s_g[1][b * 36 + ub];
            f32x4 vhn = *(const f32x4*)&s_g[2][b * 36 + ub];
            f32x4 vxn = *(const f32x4*)&s_g[3][b * 36 + ub];
            f32x4 hold = *(const f32x4*)&s_hold[b * 32 + ub];
            f32x4 hnew;
            u32 wd[4];
#pragma unroll
            for (int i = 0; i < 4; ++i) {
                float rr = fast_sigmoid(vr[i] + s_bih[ub + i] + s_bhh[ub + i]);
                float zz = fast_sigmoid(vz[i] + s_bih[32 + ub + i] +
                                        s_bhh[32 + ub + i]);
                float nn = fast_tanh(vxn[i] + s_bih[64 + ub + i] +
                                     rr * (vhn[i] + s_bhh[64 + ub + i]));
                float hv = (1.0f - zz) * nn + zz * hold[i];
                hv = fminf(fmaxf(hv, -5.0f), 5.0f);
                hnew[i] = hv;
                __bf16 hb = (__bf16)hv;
                wd[i] = (u32)__builtin_bit_cast(u16, hb);
            }
            // publish first (only these stores are outstanding at the wait)
            if (t < T_STEPS - 1) {
                u64* dst = (u64*)(hbuf + (size_t)((t + 1) & 1) * B_TOT * H_DIM +
                                  (size_t)(bg + b) * H_DIM + u0 + ub);
                u64 pk0 = (u64)wd[0] | ((u64)wd[1] << 16) |
                          ((u64)wd[2] << 32) | ((u64)wd[3] << 48);
                // NOTE: 4x bf16 fit one u64 (16b each)
                __hip_atomic_store(dst, pk0, __ATOMIC_RELAXED,
                                   __HIP_MEMORY_SCOPE_AGENT);
                asm volatile("s_waitcnt vmcnt(0)" ::: "memory");  // pub acked
            }
            *(f32x4*)&s_hold[b * 32 + ub] = hnew;
            *(f32x4*)(out + ((size_t)(bg + b) * T_STEPS + t) * H_DIM + u0 + ub)
                = hnew;
            if (t == T_STEPS - 1)
                *(f32x4*)(out + (size_t)B_TOT * T_STEPS * H_DIM +
                          (size_t)(bg + b) * H_DIM + u0 + ub) = hnew;
        }
        BAR_RAW();   // H: rendezvous; publishes of waves 0-1 acked pre-arrival

        // ---- I: flag store (after barrier => after both gate waves' acks) --
        if (tid == 0 && t < T_STEPS - 1) {
            __hip_atomic_store(flags + ((size_t)g * TPAD + t) * 16 + j,
                               (unsigned char)1, __ATOMIC_RELAXED,
                               __HIP_MEMORY_SCOPE_AGENT);
        }
    }
}

extern "C" void kernel_launch(void* const* d_in, const int* in_sizes, int n_in,
                              void* d_out, int out_size, void* d_ws, size_t ws_size,
                              hipStream_t stream) {
    const float* x   = (const float*)d_in[0];
    const float* h0  = (const float*)d_in[1];
    const float* wih = (const float*)d_in[2];
    const float* whh = (const float*)d_in[3];
    const float* bih = (const float*)d_in[4];
    const float* bhh = (const float*)d_in[5];
    float* out = (float*)d_out;
    unsigned char*  flags = (unsigned char*)d_ws;
    __hip_bfloat16* hbuf  = (__hip_bfloat16*)((char*)d_ws + FLAGS_BYTES);

    // flags must start at 0 every launch (ws is re-poisoned to 0xAA).
    hipMemsetAsync(d_ws, 0, FLAGS_BYTES, stream);

    void* args[] = { (void*)&x, (void*)&h0, (void*)&wih, (void*)&whh,
                     (void*)&bih, (void*)&bhh, (void*)&out,
                     (void*)&flags, (void*)&hbuf };
    // Cooperative launch guarantees all 256 blocks (1/CU) are co-resident,
    // which the group-local flag barriers require.
    hipLaunchCooperativeKernel((void*)gru_persist, dim3(256), dim3(384),
                               args, 0, stream);
}